// Round 3
// baseline (183.260 us; speedup 1.0000x reference)
//
#include <hip/hip_runtime.h>
#include <hip/hip_bf16.h>
#include <math.h>

typedef _Float16 f16;
typedef _Float16 f16x8 __attribute__((ext_vector_type(8)));
typedef _Float16 f16x4 __attribute__((ext_vector_type(4)));
typedef float f32x4 __attribute__((ext_vector_type(4)));

#define DIM   1024
#define NH    16
#define HD    64
#define BB    2
#define SS    4096
#define AA    512
#define SCALE 0.125f

// ---------------- workspace layout (units: f16 elements) ----------------
static const size_t OFF_XH  = 0;                       // 2*4096*1024 = 8388608
static const size_t OFF_WT  = 8388608;                 // 5 x 1048576 (Wq,Wk,Wv,Wqt,Wo transposed)
static const size_t OFF_QC  = OFF_WT + 5u*1048576u;    // 13631488, 8388608 (B,H,4096,64)
static const size_t OFF_KB  = OFF_QC + 8388608u;       // (B,H,512,64)
static const size_t OFF_VT  = OFF_KB + 1048576u;       // (B,H,64,512)
static const size_t OFF_AO  = OFF_VT + 1048576u;       // 8388608 (B,S,1024) fp16

// ---------------- cast x fp32 -> fp16 ----------------
__global__ __launch_bounds__(256) void cast_x_kernel(const float* __restrict__ x,
                                                     f16* __restrict__ xh) {
    size_t i = ((size_t)blockIdx.x * 256 + threadIdx.x) * 4;
    float4 v = *reinterpret_cast<const float4*>(x + i);
    f16x4 o;
    o[0] = (f16)v.x; o[1] = (f16)v.y; o[2] = (f16)v.z; o[3] = (f16)v.w;
    *reinterpret_cast<f16x4*>(xh + i) = o;
}

// ---------------- transpose + cast the 5 weight matrices ----------------
__global__ __launch_bounds__(256) void wcast_kernel(const float* W0, const float* W1,
                                                    const float* W2, const float* W3,
                                                    const float* W4,
                                                    f16* T0, f16* T1, f16* T2, f16* T3, f16* T4) {
    __shared__ float tile[32][33];
    const float* W; f16* T;
    switch (blockIdx.z) {
        case 0: W = W0; T = T0; break;
        case 1: W = W1; T = T1; break;
        case 2: W = W2; T = T2; break;
        case 3: W = W3; T = T3; break;
        default: W = W4; T = T4; break;
    }
    int tx = threadIdx.x, ty = threadIdx.y;      // 32 x 8
    int gx = blockIdx.x * 32, gy = blockIdx.y * 32;
#pragma unroll
    for (int i = 0; i < 32; i += 8)
        tile[ty + i][tx] = W[(size_t)(gy + ty + i) * DIM + gx + tx];
    __syncthreads();
#pragma unroll
    for (int i = 0; i < 32; i += 8)
        T[(size_t)(gx + ty + i) * DIM + gy + tx] = (f16)tile[tx][ty + i];
}

// ---------------- generic GEMM: C = A(MxK) @ Wt^T + bias ----------------
// A: fp16 row-major, rows mapped to x rows via (b, s).  Bt: fp16 (N x K) = W^T.
// mode 0: fp16 out[b][h][s+soff][d]   (head-split, sdim = S dim of out)
// mode 1: fp16 out[b][h][d][s]        (transposed V layout, A dim = 512)
// mode 2: fp32 out[b*4096+s][c] + bias (final output)
struct GemmOut {
    const f16* Bt;
    const float* bias;
    int mode;
    void* out;
    int sdim;
    int soff;
};

__global__ __launch_bounds__(256) void gemm_kernel(const f16* __restrict__ A,
                                                   int rows_per_b, int a_row_off,
                                                   GemmOut o0, GemmOut o1, GemmOut o2) {
    __shared__ __align__(16) f16 As[128][40];
    __shared__ __align__(16) f16 Bs[128][40];

    GemmOut o = (blockIdx.z == 0) ? o0 : ((blockIdx.z == 1) ? o1 : o2);

    const int t    = threadIdx.x;
    const int wid  = t >> 6;
    const int lane = t & 63;
    const int lr   = lane & 15;
    const int lg   = lane >> 4;
    const int br   = blockIdx.x, bc = blockIdx.y;

    // rows_per_b is a multiple of 128 -> whole block lives in one batch b
    const int b      = (br * 128) / rows_per_b;
    const int s_base = (br * 128) % rows_per_b;

    // staging: thread loads 2x 16B (16 halfs) of one row
    const int sr  = t >> 1;
    const int sc0 = (t & 1) * 16;
    const f16* Aptr = A + ((size_t)b * SS + a_row_off + s_base + sr) * DIM + sc0;
    const f16* Bptr = o.Bt + ((size_t)(bc * 128 + sr)) * DIM + sc0;

    const int wr = (wid >> 1) * 64;
    const int wc = (wid & 1) * 64;

    f32x4 acc[4][4] = {};

    for (int k0 = 0; k0 < DIM; k0 += 32) {
        __syncthreads();
        *reinterpret_cast<f16x8*>(&As[sr][sc0])     = *reinterpret_cast<const f16x8*>(Aptr + k0);
        *reinterpret_cast<f16x8*>(&As[sr][sc0 + 8]) = *reinterpret_cast<const f16x8*>(Aptr + k0 + 8);
        *reinterpret_cast<f16x8*>(&Bs[sr][sc0])     = *reinterpret_cast<const f16x8*>(Bptr + k0);
        *reinterpret_cast<f16x8*>(&Bs[sr][sc0 + 8]) = *reinterpret_cast<const f16x8*>(Bptr + k0 + 8);
        __syncthreads();

        f16x8 af[4], bf[4];
#pragma unroll
        for (int m = 0; m < 4; m++)
            af[m] = *reinterpret_cast<const f16x8*>(&As[wr + m * 16 + lr][lg * 8]);
#pragma unroll
        for (int n = 0; n < 4; n++)
            bf[n] = *reinterpret_cast<const f16x8*>(&Bs[wc + n * 16 + lr][lg * 8]);
#pragma unroll
        for (int m = 0; m < 4; m++)
#pragma unroll
            for (int n = 0; n < 4; n++)
                acc[m][n] = __builtin_amdgcn_mfma_f32_16x16x32_f16(af[m], bf[n], acc[m][n], 0, 0, 0);
    }

    // epilogue
#pragma unroll
    for (int m = 0; m < 4; m++) {
        const int row_local = wr + m * 16 + lg * 4;
#pragma unroll
        for (int n = 0; n < 4; n++) {
            const int c  = bc * 128 + wc + n * 16 + lr;
            const float bv = o.bias[c];
            const int h = c >> 6, d = c & 63;
#pragma unroll
            for (int q = 0; q < 4; q++) {
                const int s_local = s_base + row_local + q;
                const float val = acc[m][n][q] + bv;
                if (o.mode == 2) {
                    ((float*)o.out)[((size_t)b * SS + o.soff + s_local) * DIM + c] = val;
                } else if (o.mode == 0) {
                    const int out_s = o.soff + s_local;
                    ((f16*)o.out)[(((size_t)(b * NH + h)) * o.sdim + out_s) * HD + d] = (f16)val;
                } else { // mode 1: transposed V
                    ((f16*)o.out)[(((size_t)(b * NH + h)) * HD + d) * AA + (o.soff + s_local)] = (f16)val;
                }
            }
        }
    }
}

// ---------------- fused anchor attention ----------------
// qc: (B,H,4096,64) fp16   kb: (B,H,512,64) fp16   vt: (B,H,64,512) fp16
// ao: (B,S,1024) fp16 (head-interleaved columns)
__global__ __launch_bounds__(256) void attn_kernel(const f16* __restrict__ qc,
                                                   const f16* __restrict__ kb,
                                                   const f16* __restrict__ vt,
                                                   f16* __restrict__ ao) {
    __shared__ __align__(16) f16 Qs[64][72];
    __shared__ __align__(16) f16 Ks[64][72];
    __shared__ __align__(16) f16 Vs[64][72];
    __shared__ __align__(16) f16 Ps[4][16][72];

    const int t    = threadIdx.x;
    const int wid  = t >> 6;
    const int lane = t & 63;
    const int lr   = lane & 15;
    const int lg   = lane >> 4;
    const int qt   = blockIdx.x;  // 64 q-tiles of 64 rows
    const int h    = blockIdx.y;
    const int b    = blockIdx.z;
    const size_t bh = (size_t)b * NH + h;

    // stage Q tile (64 x 64)
    {
        const int r = t >> 2, c0 = (t & 3) * 16;
        const f16* src = qc + (bh * SS + qt * 64 + r) * HD + c0;
        *reinterpret_cast<f16x8*>(&Qs[r][c0])     = *reinterpret_cast<const f16x8*>(src);
        *reinterpret_cast<f16x8*>(&Qs[r][c0 + 8]) = *reinterpret_cast<const f16x8*>(src + 8);
    }

    f32x4 acc[4] = {};
    float mrow[4] = {-INFINITY, -INFINITY, -INFINITY, -INFINITY};
    float lrow[4] = {0.f, 0.f, 0.f, 0.f};
    __syncthreads();

    for (int at = 0; at < AA / 64; ++at) {
        // stage K tile (64 anchors x 64 d) and Vt tile (64 d x 64 anchors)
        {
            const int r = t >> 2, c0 = (t & 3) * 16;
            const f16* ksrc = kb + (bh * AA + at * 64 + r) * HD + c0;
            *reinterpret_cast<f16x8*>(&Ks[r][c0])     = *reinterpret_cast<const f16x8*>(ksrc);
            *reinterpret_cast<f16x8*>(&Ks[r][c0 + 8]) = *reinterpret_cast<const f16x8*>(ksrc + 8);
            const f16* vsrc = vt + (bh * HD + r) * AA + at * 64 + c0;
            *reinterpret_cast<f16x8*>(&Vs[r][c0])     = *reinterpret_cast<const f16x8*>(vsrc);
            *reinterpret_cast<f16x8*>(&Vs[r][c0 + 8]) = *reinterpret_cast<const f16x8*>(vsrc + 8);
        }
        __syncthreads();

        // S = Q K^T * scale   (wave wid owns 16 q-rows)
        f16x8 qa0 = *reinterpret_cast<const f16x8*>(&Qs[wid * 16 + lr][lg * 8]);
        f16x8 qa1 = *reinterpret_cast<const f16x8*>(&Qs[wid * 16 + lr][32 + lg * 8]);
        f32x4 s[4];
#pragma unroll
        for (int n = 0; n < 4; n++) {
            f16x8 kf0 = *reinterpret_cast<const f16x8*>(&Ks[n * 16 + lr][lg * 8]);
            f16x8 kf1 = *reinterpret_cast<const f16x8*>(&Ks[n * 16 + lr][32 + lg * 8]);
            f32x4 z = {};
            z = __builtin_amdgcn_mfma_f32_16x16x32_f16(qa0, kf0, z, 0, 0, 0);
            z = __builtin_amdgcn_mfma_f32_16x16x32_f16(qa1, kf1, z, 0, 0, 0);
#pragma unroll
            for (int q = 0; q < 4; q++) s[n][q] = z[q] * SCALE;
        }

        // online softmax update (row = lg*4 + r, cols spread over 16 lanes sharing lg)
#pragma unroll
        for (int r = 0; r < 4; r++) {
            float tm = fmaxf(fmaxf(s[0][r], s[1][r]), fmaxf(s[2][r], s[3][r]));
#pragma unroll
            for (int off = 1; off < 16; off <<= 1) tm = fmaxf(tm, __shfl_xor(tm, off));
            const float mn = fmaxf(mrow[r], tm);
            const float sc = __expf(mrow[r] - mn);
            float rs = 0.f;
#pragma unroll
            for (int n = 0; n < 4; n++) {
                float p = __expf(s[n][r] - mn);
                s[n][r] = p;
                rs += p;
            }
#pragma unroll
            for (int off = 1; off < 16; off <<= 1) rs += __shfl_xor(rs, off);
            lrow[r] = lrow[r] * sc + rs;
            mrow[r] = mn;
#pragma unroll
            for (int n = 0; n < 4; n++) acc[n][r] *= sc;
        }

        // P (C-layout) -> LDS -> A-fragment layout
#pragma unroll
        for (int r = 0; r < 4; r++)
#pragma unroll
            for (int n = 0; n < 4; n++)
                Ps[wid][lg * 4 + r][n * 16 + lr] = (f16)s[n][r];
        __syncthreads();

        f16x8 pa0 = *reinterpret_cast<const f16x8*>(&Ps[wid][lr][lg * 8]);
        f16x8 pa1 = *reinterpret_cast<const f16x8*>(&Ps[wid][lr][32 + lg * 8]);
#pragma unroll
        for (int n = 0; n < 4; n++) {
            f16x8 vf0 = *reinterpret_cast<const f16x8*>(&Vs[n * 16 + lr][lg * 8]);
            f16x8 vf1 = *reinterpret_cast<const f16x8*>(&Vs[n * 16 + lr][32 + lg * 8]);
            acc[n] = __builtin_amdgcn_mfma_f32_16x16x32_f16(pa0, vf0, acc[n], 0, 0, 0);
            acc[n] = __builtin_amdgcn_mfma_f32_16x16x32_f16(pa1, vf1, acc[n], 0, 0, 0);
        }
        __syncthreads();
    }

    // epilogue: normalize and write (B,S,1024) fp16
#pragma unroll
    for (int r = 0; r < 4; r++) {
        const float inv = 1.0f / lrow[r];
        const int row = qt * 64 + wid * 16 + lg * 4 + r;
#pragma unroll
        for (int n = 0; n < 4; n++) {
            ao[((size_t)b * SS + row) * DIM + h * HD + n * 16 + lr] = (f16)(acc[n][r] * inv);
        }
    }
}

// ---------------- launch ----------------
extern "C" void kernel_launch(void* const* d_in, const int* in_sizes, int n_in,
                              void* d_out, int out_size, void* d_ws, size_t ws_size,
                              hipStream_t stream) {
    const float* x   = (const float*)d_in[0];
    const float* Wq  = (const float*)d_in[1];
    const float* bq  = (const float*)d_in[2];
    const float* Wk  = (const float*)d_in[3];
    const float* bk  = (const float*)d_in[4];
    const float* Wv  = (const float*)d_in[5];
    const float* bv  = (const float*)d_in[6];
    const float* Wqt = (const float*)d_in[7];
    const float* bqt = (const float*)d_in[8];
    const float* Wo  = (const float*)d_in[9];
    const float* bo  = (const float*)d_in[10];

    f16* ws   = (f16*)d_ws;
    f16* xh   = ws + OFF_XH;
    f16* wtq  = ws + OFF_WT;
    f16* wtk  = wtq + 1048576u;
    f16* wtv  = wtk + 1048576u;
    f16* wtqt = wtv + 1048576u;
    f16* wto  = wtqt + 1048576u;
    f16* qc   = ws + OFF_QC;
    f16* kbuf = ws + OFF_KB;
    f16* vtb  = ws + OFF_VT;
    f16* ao   = ws + OFF_AO;

    cast_x_kernel<<<8192, 256, 0, stream>>>(x, xh);
    wcast_kernel<<<dim3(32, 32, 5), dim3(32, 8), 0, stream>>>(Wq, Wk, Wv, Wqt, Wo,
                                                              wtq, wtk, wtv, wtqt, wto);

    GemmOut oq { wtq, bq, 0, qc,   SS, 0 };
    GemmOut ok { wtk, bk, 0, kbuf, AA, 0 };
    GemmOut ov { wtv, bv, 1, vtb,  AA, 0 };
    gemm_kernel<<<dim3(8, 8, 3), 256, 0, stream>>>(xh, 512, 0, oq, ok, ov);

    GemmOut oqt { wtqt, bqt, 0, qc, SS, 512 };
    gemm_kernel<<<dim3(56, 8, 1), 256, 0, stream>>>(xh, 3584, 512, oqt, oqt, oqt);

    attn_kernel<<<dim3(64, NH, BB), 256, 0, stream>>>(qc, kbuf, vtb, ao);

    GemmOut oo { wto, bo, 2, d_out, SS, 0 };
    gemm_kernel<<<dim3(64, 8, 1), 256, 0, stream>>>(ao, 4096, 0, oo, oo, oo);
}